// Round 2
// baseline (403.564 us; speedup 1.0000x reference)
//
#include <hip/hip_runtime.h>

// NNLS via normal equations + FISTA.
// Phase 1: M = U^T U, U = [X | y | 1] (2e6 x 37). 8x8 per-lane patches,
//          4 teams/wave. ROUND 2: global_load_lds DMA staging into
//          double-buffered LDS (1 barrier/step, no VGPR round-trip, no
//          ds_write phase). Linear [64][32] X-buffer with XOR chunk swizzle
//          (chunk' = chunk ^ (row&7)) applied on BOTH the DMA source address
//          and the read side (involution) -> <=2-way LDS conflicts (free).
//          y in a separate linear [64][4] buffer; ones column is an analytic
//          (1,0,0,0) fragment for PJ=4 patches. Grid 1024 = 4 blocks/CU.
// Phase 1b: atomic-free coalesced reduction of per-block partials (transposed
//           layout) into the 40x40 Gram, one block per entry.
// Phase 2: power iteration (8) + FISTA (32); LDS-broadcast matvec, one wave
//          per output column. kappa(G)~1.016 -> fp32-converged well before 32.
//
// NOTE (round 1 counters): ~308 us of the 391.5 us total is the harness's
// 2x 1GB workspace poison fill (6.6 TB/s each) inside the timed region.
// Our kernels are ~83 us; gram ~68 us vs a 46 us memory floor.

#define NROWS 2000000
#define TR 64                 // tile rows
#define NT (NROWS / TR)       // 31250 tiles, exact
#define GB 1024               // gram blocks (4 blocks/CU)
#define PITERS 8
#define QPITERS 32

// LDS float offsets: Xbuf[2][64][32] at 0 / 2048, Ybuf[2][64][4] at 4096 / 4352.
#define XB(buf) ((buf) ? 2048 : 0)
#define YB(buf) (4096 + ((buf) ? 256 : 0))

__device__ __forceinline__ void lds_dma16(const float* g, float* l) {
  // 16B per lane, LDS dest = wave-uniform base + lane*16
  __builtin_amdgcn_global_load_lds((const __attribute__((address_space(1))) void*)g,
                                   (__attribute__((address_space(3))) void*)l,
                                   16, 0, 0);
}

// u-row layout: [x0..x31 | y0..y3 | 1 | 0 0 0] = cols 0..39
__global__ __launch_bounds__(256) void gram_kernel(const float* __restrict__ X,
                                                   const float* __restrict__ Yg,
                                                   float* __restrict__ Pw) {
  __shared__ float sm[4608];  // 18 KB: 2x8KB Xbuf + 2x1KB Ybuf; epilogue overlays 3840 floats
  const int tid  = threadIdx.x;
  const int lane = tid & 63;
  const int wv   = tid >> 6;
  const int team = lane >> 4;   // 4 teams of 16 lanes
  const int p    = lane & 15;   // patch id; 15 active

  // patch p -> (PI,PJ) in upper triangle of the 5x5 grid of 8x8 col-blocks
  int pp = (p < 15) ? p : 0;
  int PI = 0, rem = pp;
  while (rem >= 5 - PI) { rem -= 5 - PI; ++PI; }
  const int PJ = PI + rem;
  const int PI2 = PI * 2, PJ2 = PJ * 2;
  const bool aX = (PI < 4);     // a-fragment comes from Xbuf (else y/ones)
  const bool bX = (PJ < 4);

  // DMA source addressing (pre-swizzled): lane covers LDS slot l*16 of its
  // segment; slot chunk s = l&7 must hold content chunk c = s ^ (row&7),
  // and row&7 == l>>3 for every segment.
  const int drow0 = (wv * 2 + 0) * 8 + (lane >> 3);
  const int drow1 = (wv * 2 + 1) * 8 + (lane >> 3);
  const int dc    = ((lane & 7) ^ (lane >> 3)) * 4;
  const float* gx0 = X  + (size_t)((size_t)blockIdx.x * TR + drow0) * 32 + dc;
  const float* gx1 = X  + (size_t)((size_t)blockIdx.x * TR + drow1) * 32 + dc;
  const float* gy  = Yg + (size_t)((size_t)blockIdx.x * TR + lane) * 4;
  const size_t xstride = (size_t)GB * TR * 32;
  const size_t ystride = (size_t)GB * TR * 4;

  float acc[8][8];
#pragma unroll
  for (int a = 0; a < 8; ++a)
#pragma unroll
    for (int b = 0; b < 8; ++b) acc[a][b] = 0.f;

  const int rbase = wv * 16 + team;
  const float4 onesfrag = make_float4(1.f, 0.f, 0.f, 0.f);

  // prologue: DMA tile 0 into buffer 0
  int tile = blockIdx.x;
  lds_dma16(gx0, &sm[XB(0) + (wv * 2 + 0) * 256]);
  lds_dma16(gx1, &sm[XB(0) + (wv * 2 + 1) * 256]);
  if (wv == 0) lds_dma16(gy, &sm[YB(0)]);
  gx0 += xstride; gx1 += xstride; gy += ystride;
  __syncthreads();  // vmcnt(0) drain -> buffer 0 loaded

  int buf = 0;
  while (tile < NT) {
    const int nt = tile + GB;
    if (nt < NT) {  // DMA next tile into the other buffer (readers done last barrier)
      const int xn = XB(buf ^ 1);
      lds_dma16(gx0, &sm[xn + (wv * 2 + 0) * 256]);
      lds_dma16(gx1, &sm[xn + (wv * 2 + 1) * 256]);
      if (wv == 0) lds_dma16(gy, &sm[YB(buf ^ 1)]);
      gx0 += xstride; gx1 += xstride; gy += ystride;
    }

    const int Xc = XB(buf), Yc = YB(buf);
#pragma unroll
    for (int rs = 0; rs < 4; ++rs) {
      const int r = rbase + rs * 4;
      const int e = r & 7;
      const int xrow = Xc + r * 32;
      const int yrow = Yc + r * 4;
      // swizzled read: chunk c lives at slot c^e
      const int a0o = aX ? xrow + ((PI2    ) ^ e) * 4 : yrow;
      const int a1o = aX ? xrow + ((PI2 | 1) ^ e) * 4 : yrow;
      const int b0o = bX ? xrow + ((PJ2    ) ^ e) * 4 : yrow;
      const int b1o = bX ? xrow + ((PJ2 | 1) ^ e) * 4 : yrow;
      float4 a0 = *(const float4*)&sm[a0o];
      float4 a1 = *(const float4*)&sm[a1o];
      float4 b0 = *(const float4*)&sm[b0o];
      float4 b1 = *(const float4*)&sm[b1o];
      if (!aX) a1 = onesfrag;   // u[36..39] = [1,0,0,0]
      if (!bX) b1 = onesfrag;
      float av[8] = {a0.x, a0.y, a0.z, a0.w, a1.x, a1.y, a1.z, a1.w};
      float bv[8] = {b0.x, b0.y, b0.z, b0.w, b1.x, b1.y, b1.z, b1.w};
#pragma unroll
      for (int a = 0; a < 8; ++a)
#pragma unroll
        for (int b = 0; b < 8; ++b) acc[a][b] = fmaf(av[a], bv[b], acc[a][b]);
    }

    __syncthreads();  // drains next-tile DMA (vmcnt 0) + all waves done reading buf
    buf ^= 1;
    tile = nt;
  }

  // cross-team reduce (lane bits 4,5), then transposed partial store:
  // Pw[e*GB + block] -> reduce_kernel reads coalesced
#pragma unroll
  for (int a = 0; a < 8; ++a)
#pragma unroll
    for (int b = 0; b < 8; ++b) {
      float v = acc[a][b];
      v += __shfl_xor(v, 16);
      v += __shfl_xor(v, 32);
      acc[a][b] = v;
    }
  __syncthreads();
  if (p < 15 && team == 0) {
#pragma unroll
    for (int a = 0; a < 8; ++a)
#pragma unroll
      for (int b = 0; b < 8; ++b)
        sm[wv * 960 + p * 64 + a * 8 + b] = acc[a][b];
  }
  __syncthreads();
  for (int e = tid; e < 960; e += 256)
    Pw[(size_t)e * GB + blockIdx.x] = sm[e] + sm[e + 960] + sm[e + 1920] + sm[e + 2880];
}

// One block per Gram entry; coalesced fold of GB partials; scatter into 40x40.
__global__ __launch_bounds__(256) void reduce_kernel(const float* __restrict__ Pw,
                                                     float* __restrict__ Mw) {
  __shared__ float red[4];
  const int t   = blockIdx.x;       // entry 0..959
  const int tid = threadIdx.x;
  float s = 0.f;
#pragma unroll
  for (int k = 0; k < GB / 256; ++k) s += Pw[(size_t)t * GB + k * 256 + tid];
#pragma unroll
  for (int off = 32; off; off >>= 1) s += __shfl_xor(s, off);
  if ((tid & 63) == 0) red[tid >> 6] = s;
  __syncthreads();
  if (tid == 0) {
    float sum = red[0] + red[1] + red[2] + red[3];
    int pe = t >> 6, idx = t & 63;
    int bi = 0, r2 = pe;
    while (r2 >= 5 - bi) { r2 -= 5 - bi; ++bi; }
    const int bj = bi + r2;
    Mw[(bi * 8 + (idx >> 3)) * 40 + (bj * 8 + (idx & 7))] = sum;
  }
}

// dot of 36-float register row with 36-float LDS vector (uniform addr = broadcast)
__device__ __forceinline__ float dot36(const float* __restrict__ Gr, const float4* __restrict__ y4) {
  float g0 = 0.f, g1 = 0.f, g2 = 0.f, g3 = 0.f;
#pragma unroll
  for (int c = 0; c < 9; ++c) {
    float4 y = y4[c];
    g0 = fmaf(Gr[c * 4 + 0], y.x, g0);
    g1 = fmaf(Gr[c * 4 + 1], y.y, g1);
    g2 = fmaf(Gr[c * 4 + 2], y.z, g2);
    g3 = fmaf(Gr[c * 4 + 3], y.w, g3);
  }
  return (g0 + g1) + (g2 + g3);
}

__device__ __forceinline__ float wave_sum(float x) {
#pragma unroll
  for (int off = 32; off; off >>= 1) x += __shfl_xor(x, off);
  return x;
}

// A-col a in [0,33): U(a) = a<32 ? a : 36. c columns = u-cols 32..35.
// M holds upper 8x8 blocks only: mirror via (Ui>>3) vs (Uk>>3).
__global__ __launch_bounds__(256) void solve_kernel(const float* __restrict__ Mw,
                                                    float* __restrict__ out) {
  __shared__ float4 Yb4[2][4][9];
  const int tid  = threadIdx.x;
  const int lane = tid & 63;
  const int col  = tid >> 6;       // one wave per output column
  const bool act = lane < 33;
  const int i  = act ? lane : 0;
  const int Ui = (i < 32) ? i : 36;

  float Gr[36];
#pragma unroll
  for (int k = 0; k < 33; ++k) {
    const int Uk = (k < 32) ? k : 36;
    Gr[k] = ((Ui >> 3) <= (Uk >> 3)) ? Mw[Ui * 40 + Uk] : Mw[Uk * 40 + Ui];
  }
  Gr[33] = Gr[34] = Gr[35] = 0.f;
  const float ci = Mw[Ui * 40 + 32 + col];

  if (lane < 9) {
    Yb4[0][col][lane] = make_float4(0.f, 0.f, 0.f, 0.f);
    Yb4[1][col][lane] = make_float4(0.f, 0.f, 0.f, 0.f);
  }
  __syncthreads();
  float v = rsqrtf(33.f);
  if (act) ((float*)&Yb4[0][col][0])[i] = v;
  __syncthreads();

  // power iteration for step; Rayleigh quotient <= lambda_max, so step >= 1/L;
  // any step in (0, 2/L) converges to the same QP fixed point (kappa ~ 1.016)
  for (int it = 0; it < PITERS; ++it) {
    const int rb = it & 1;
    float w = dot36(Gr, &Yb4[rb][col][0]);
    float x = wave_sum(act ? w * w : 0.f);
    float vn = w * rsqrtf(x);
    if (act) ((float*)&Yb4[rb ^ 1][col][0])[i] = vn;
    v = vn;
    __syncthreads();
  }
  {
    const int rb = PITERS & 1;
    float w = dot36(Gr, &Yb4[rb][col][0]);
    v = wave_sum(act ? v * w : 0.f);  // v^T G v
  }
  const float step = 1.f / v;

  __syncthreads();
  if (act) ((float*)&Yb4[0][col][0])[i] = 0.f;
  __syncthreads();

  float Z = 0.f, Yv = 0.f, t = 1.f;
  for (int it = 0; it < QPITERS; ++it) {
    const int rb = it & 1;
    float g = dot36(Gr, &Yb4[rb][col][0]);
    float zn = Yv - step * (g - ci);
    if (lane < 32) zn = fmaxf(zn, 0.f);  // W rows clamped; bias row free
    float tn = 0.5f * (1.f + sqrtf(fmaf(4.f * t, t, 1.f)));
    float beta = (t - 1.f) / tn;
    float yn = fmaf(beta, zn - Z, zn);
    if (act) ((float*)&Yb4[rb ^ 1][col][0])[i] = yn;
    Z = zn; Yv = yn; t = tn;
    __syncthreads();
  }
  if (lane < 32) out[lane * 4 + col] = Z;  // W is [32,4] row-major
}

extern "C" void kernel_launch(void* const* d_in, const int* in_sizes, int n_in,
                              void* d_out, int out_size, void* d_ws, size_t ws_size,
                              hipStream_t stream) {
  const float* X  = (const float*)d_in[0];
  const float* Yg = (const float*)d_in[1];
  float* Pw  = (float*)d_ws;                 // 960*GB floats of partials (transposed)
  float* Mw  = Pw + (size_t)960 * GB;        // 40x40 Gram (upper blocks)
  float* out = (float*)d_out;

  hipLaunchKernelGGL(gram_kernel,   dim3(GB),  dim3(256), 0, stream, X, Yg, Pw);
  hipLaunchKernelGGL(reduce_kernel, dim3(960), dim3(256), 0, stream, Pw, Mw);
  hipLaunchKernelGGL(solve_kernel,  dim3(1),   dim3(256), 0, stream, Mw, out);
}